// Round 1
// baseline (690.006 us; speedup 1.0000x reference)
//
#include <hip/hip_runtime.h>
#include <hip/hip_bf16.h>

#define T_TOK 2048
#define D_DIM 1024
#define E_NUM 16
#define K_TOP 4
#define I_DIM 512
#define TWOI  1024

// ---------------- Kernel 1: router logits + top-4 + combine weights ----------
__global__ __launch_bounds__(256) void router_topk_kernel(
    const float* __restrict__ x, const float* __restrict__ router,
    const float* __restrict__ rbias,
    int* __restrict__ sel_idx, float* __restrict__ sel_w, int* __restrict__ counts)
{
    const int t = blockIdx.x;
    const int tid = threadIdx.x;
    float acc[E_NUM];
#pragma unroll
    for (int e = 0; e < E_NUM; ++e) acc[e] = 0.f;
    const float* xr = x + (size_t)t * D_DIM;
    for (int d = tid; d < D_DIM; d += 256) {
        const float xv = xr[d];
        const float* rr = router + (size_t)d * E_NUM;
#pragma unroll
        for (int e = 0; e < E_NUM; ++e) acc[e] += xv * rr[e];
    }
    __shared__ float red[E_NUM][256];
#pragma unroll
    for (int e = 0; e < E_NUM; ++e) red[e][tid] = acc[e];
    __syncthreads();
    for (int s = 128; s > 0; s >>= 1) {
        if (tid < s) {
#pragma unroll
            for (int e = 0; e < E_NUM; ++e) red[e][tid] += red[e][tid + s];
        }
        __syncthreads();
    }
    if (tid == 0) {
        float logit[E_NUM], biased[E_NUM];
#pragma unroll
        for (int e = 0; e < E_NUM; ++e) { logit[e] = red[e][0]; biased[e] = logit[e] + rbias[e]; }
        bool used[E_NUM];
#pragma unroll
        for (int e = 0; e < E_NUM; ++e) used[e] = false;
        int selv[K_TOP]; float wv[K_TOP]; float wsum = 0.f;
        for (int k = 0; k < K_TOP; ++k) {
            int bi = 0; float best = -1e30f;
            for (int e = 0; e < E_NUM; ++e)
                if (!used[e] && biased[e] > best) { best = biased[e]; bi = e; }
            used[bi] = true; selv[k] = bi;
            const float s = 1.f / (1.f + expf(-logit[bi]));
            wv[k] = s; wsum += s;
        }
        for (int k = 0; k < K_TOP; ++k) {
            sel_idx[t * K_TOP + k] = selv[k];
            sel_w[t * K_TOP + k] = wv[k] / wsum;
            atomicAdd(&counts[selv[k]], 1);
        }
    }
}

// ---------------- Kernel 2: prefix scan + counts/entropy outputs -------------
__global__ void scan_stats_kernel(const int* __restrict__ counts,
                                  int* __restrict__ offsets, int* __restrict__ cursor,
                                  float* __restrict__ out_tail)
{
    if (threadIdx.x == 0 && blockIdx.x == 0) {
        int off = 0;
        float tot = 0.f;
        for (int e = 0; e < E_NUM; ++e) {
            offsets[e] = off; cursor[e] = off; off += counts[e];
            tot += (float)counts[e];
        }
        offsets[E_NUM] = off;
        const float total = fmaxf(tot, 1.f);
        float ent = 0.f;
        for (int e = 0; e < E_NUM; ++e) {
            const float c = (float)counts[e];
            const float frac = c / total;
            ent -= frac * logf(frac + 1e-6f);
            out_tail[e] = c;
        }
        out_tail[E_NUM] = ent;
    }
}

// ---------------- Kernel 3: build expert-grouped row permutation -------------
__global__ void scatter_kernel(const int* __restrict__ sel_idx,
                               int* __restrict__ cursor, int* __restrict__ perm)
{
    const int i = blockIdx.x * 256 + threadIdx.x;
    if (i >= T_TOK * K_TOP) return;
    const int e = sel_idx[i];
    const int pos = atomicAdd(&cursor[e], 1);
    perm[pos] = i;   // i = t*K + k
}

// ---------------- Kernel 4: gathered gate/up GEMM + SiLU*u*weight ------------
// Per block: 64 rows x (64 g-cols + 64 u-cols), K-loop over D in steps of 16.
__global__ __launch_bounds__(256) void gate_gemm_kernel(
    const float* __restrict__ x, const float* __restrict__ wgu,
    const int* __restrict__ offsets, const int* __restrict__ perm,
    const float* __restrict__ sel_w, float* __restrict__ h)
{
    const int e = blockIdx.z;
    const int base = offsets[e];
    const int nrows = offsets[e + 1] - base;
    const int m0 = blockIdx.y * 64;
    if (m0 >= nrows) return;
    const int c0 = blockIdx.x * 64;           // 0..511 step 64
    const int tid = threadIdx.x;

    __shared__ float As[16][64];              // [k][row]
    __shared__ float Bg[16][64];              // [k][col]
    __shared__ float Bu[16][64];

    // A-load mapping: 4 consecutive floats per thread
    const int lrow = tid >> 2;                // 0..63
    const int c4 = (tid & 3) * 4;             // 0,4,8,12
    const int grow = m0 + lrow;
    const bool arow_ok = (grow < nrows);
    const float* xrow = nullptr;
    if (arow_ok) {
        const int pv = perm[base + grow];
        xrow = x + (size_t)(pv >> 2) * D_DIM; // token id = pv/K
    }
    // B-load mapping
    const int bcol = tid & 63;
    const int brow0 = tid >> 6;               // 0..3
    const float* wbase = wgu + (size_t)e * D_DIM * TWOI;

    const int tx = tid & 15, ty = tid >> 4;
    float accg[4][4] = {}, accu[4][4] = {};

    for (int d0 = 0; d0 < D_DIM; d0 += 16) {
        float4 av = make_float4(0.f, 0.f, 0.f, 0.f);
        if (arow_ok) av = *reinterpret_cast<const float4*>(xrow + d0 + c4);
        As[c4 + 0][lrow] = av.x; As[c4 + 1][lrow] = av.y;
        As[c4 + 2][lrow] = av.z; As[c4 + 3][lrow] = av.w;
#pragma unroll
        for (int r = 0; r < 4; ++r) {
            const int dd = d0 + brow0 + r * 4;
            const float* wr = wbase + (size_t)dd * TWOI;
            Bg[brow0 + r * 4][bcol] = wr[c0 + bcol];
            Bu[brow0 + r * 4][bcol] = wr[c0 + 512 + bcol];
        }
        __syncthreads();
#pragma unroll
        for (int kk = 0; kk < 16; ++kk) {
            const float4 a  = *reinterpret_cast<const float4*>(&As[kk][ty * 4]);
            const float4 bg = *reinterpret_cast<const float4*>(&Bg[kk][tx * 4]);
            const float4 bu = *reinterpret_cast<const float4*>(&Bu[kk][tx * 4]);
            const float aa[4] = { a.x, a.y, a.z, a.w };
            const float gg[4] = { bg.x, bg.y, bg.z, bg.w };
            const float uu[4] = { bu.x, bu.y, bu.z, bu.w };
#pragma unroll
            for (int i2 = 0; i2 < 4; ++i2)
#pragma unroll
                for (int j = 0; j < 4; ++j) {
                    accg[i2][j] += aa[i2] * gg[j];
                    accu[i2][j] += aa[i2] * uu[j];
                }
        }
        __syncthreads();
    }
    // epilogue: h[p][c] = silu(g)*u*combine_w
#pragma unroll
    for (int i2 = 0; i2 < 4; ++i2) {
        const int r = ty * 4 + i2;
        const int gr = m0 + r;
        if (gr < nrows) {
            const int pv = perm[base + gr];
            const float wgt = sel_w[pv];
            float* hrow = h + (size_t)(base + gr) * I_DIM + c0;
#pragma unroll
            for (int j = 0; j < 4; ++j) {
                const float g = accg[i2][j];
                const float u = accu[i2][j];
                const float s = g / (1.f + expf(-g));
                hrow[tx * 4 + j] = s * u * wgt;
            }
        }
    }
}

// ---------------- Kernel 5: grouped down GEMM + atomic scatter-add -----------
__global__ __launch_bounds__(256) void down_gemm_kernel(
    const float* __restrict__ h, const float* __restrict__ wdn,
    const int* __restrict__ offsets, const int* __restrict__ perm,
    float* __restrict__ y)
{
    const int e = blockIdx.z;
    const int base = offsets[e];
    const int nrows = offsets[e + 1] - base;
    const int m0 = blockIdx.y * 64;
    if (m0 >= nrows) return;
    const int c0 = blockIdx.x * 64;           // 0..1023 step 64
    const int tid = threadIdx.x;

    __shared__ float As[16][64];
    __shared__ float Bs[16][64];

    const int lrow = tid >> 2;
    const int c4 = (tid & 3) * 4;
    const int grow = m0 + lrow;
    const bool arow_ok = (grow < nrows);
    const float* hrow = arow_ok ? (h + (size_t)(base + grow) * I_DIM) : nullptr;

    const int bcol = tid & 63;
    const int brow0 = tid >> 6;
    const float* wbase = wdn + (size_t)e * I_DIM * D_DIM;

    const int tx = tid & 15, ty = tid >> 4;
    float acc[4][4] = {};

    for (int d0 = 0; d0 < I_DIM; d0 += 16) {
        float4 av = make_float4(0.f, 0.f, 0.f, 0.f);
        if (arow_ok) av = *reinterpret_cast<const float4*>(hrow + d0 + c4);
        As[c4 + 0][lrow] = av.x; As[c4 + 1][lrow] = av.y;
        As[c4 + 2][lrow] = av.z; As[c4 + 3][lrow] = av.w;
#pragma unroll
        for (int r = 0; r < 4; ++r) {
            const int dd = d0 + brow0 + r * 4;
            Bs[brow0 + r * 4][bcol] = wbase[(size_t)dd * D_DIM + c0 + bcol];
        }
        __syncthreads();
#pragma unroll
        for (int kk = 0; kk < 16; ++kk) {
            const float4 a = *reinterpret_cast<const float4*>(&As[kk][ty * 4]);
            const float4 b = *reinterpret_cast<const float4*>(&Bs[kk][tx * 4]);
            const float aa[4] = { a.x, a.y, a.z, a.w };
            const float bb[4] = { b.x, b.y, b.z, b.w };
#pragma unroll
            for (int i2 = 0; i2 < 4; ++i2)
#pragma unroll
                for (int j = 0; j < 4; ++j)
                    acc[i2][j] += aa[i2] * bb[j];
        }
        __syncthreads();
    }
#pragma unroll
    for (int i2 = 0; i2 < 4; ++i2) {
        const int r = ty * 4 + i2;
        const int gr = m0 + r;
        if (gr < nrows) {
            const int pv = perm[base + gr];
            const int t = pv >> 2;
            float* yrow = y + (size_t)t * D_DIM + c0;
#pragma unroll
            for (int j = 0; j < 4; ++j)
                atomicAdd(&yrow[tx * 4 + j], acc[i2][j]);
        }
    }
}

// ---------------- launch -----------------------------------------------------
extern "C" void kernel_launch(void* const* d_in, const int* in_sizes, int n_in,
                              void* d_out, int out_size, void* d_ws, size_t ws_size,
                              hipStream_t stream)
{
    const float* x      = (const float*)d_in[0];
    const float* router = (const float*)d_in[1];
    const float* rbias  = (const float*)d_in[2];
    const float* wgu    = (const float*)d_in[3];
    const float* wdn    = (const float*)d_in[4];
    float* out = (float*)d_out;

    char* ws = (char*)d_ws;
    int*   sel_idx = (int*)(ws + 0);            // 8192 ints
    float* sel_w   = (float*)(ws + 32768);      // 8192 floats
    int*   counts  = (int*)(ws + 65536);        // 16
    int*   offsets = counts + 16;               // 17
    int*   cursor  = offsets + 17;              // 16
    int*   perm    = (int*)(ws + 65792);        // 8192 ints
    float* h       = (float*)(ws + 131072);     // 8192*512 floats (16.8 MB)

    hipMemsetAsync(counts, 0, 16 * sizeof(int), stream);
    hipMemsetAsync(d_out, 0, (size_t)T_TOK * D_DIM * sizeof(float), stream);

    router_topk_kernel<<<T_TOK, 256, 0, stream>>>(x, router, rbias, sel_idx, sel_w, counts);
    scan_stats_kernel<<<1, 32, 0, stream>>>(counts, offsets, cursor,
                                            out + (size_t)T_TOK * D_DIM);
    scatter_kernel<<<(T_TOK * K_TOP + 255) / 256, 256, 0, stream>>>(sel_idx, cursor, perm);

    dim3 g1(8, 32, E_NUM);    // col-tiles (I/64), row-tiles (worst case T/64), experts
    gate_gemm_kernel<<<g1, 256, 0, stream>>>(x, wgu, offsets, perm, sel_w, h);

    dim3 g2(16, 32, E_NUM);   // col-tiles (D/64), row-tiles, experts
    down_gemm_kernel<<<g2, 256, 0, stream>>>(h, wdn, offsets, perm, out);
}

// Round 4
// 373.247 us; speedup vs baseline: 1.8487x; 1.8487x over previous
//
#include <hip/hip_runtime.h>
#include <hip/hip_bf16.h>
#include <cstdint>

#define T_TOK 2048
#define D_DIM 1024
#define E_NUM 16
#define K_TOP 4
#define I_DIM 512
#define TWOI  1024

typedef __bf16 bf16x8 __attribute__((ext_vector_type(8)));
typedef __bf16 bf16x4 __attribute__((ext_vector_type(4)));
typedef float  f32x4  __attribute__((ext_vector_type(4)));

__device__ __forceinline__ void gload_lds16(const void* g, void* l) {
    __builtin_amdgcn_global_load_lds(
        (const __attribute__((address_space(1))) void*)(uintptr_t)(g),
        (__attribute__((address_space(3))) void*)(uintptr_t)(l),
        16, 0, 0);
}

// ---------------- Router: one wave per token, fp32 exact -----------------
__global__ __launch_bounds__(256) void router_wave_kernel(
    const float* __restrict__ x, const float* __restrict__ router,
    const float* __restrict__ rbias,
    int* __restrict__ sel_idx, float* __restrict__ sel_w, int* __restrict__ counts)
{
    const int wv = threadIdx.x >> 6;
    const int lane = threadIdx.x & 63;
    const int t = blockIdx.x * 4 + wv;
    if (t >= T_TOK) return;
    const int e = lane & 15, dg = lane >> 4;

    const float* xp = x + (size_t)t * D_DIM + dg * 256;
    const float* rp = router + (size_t)(dg * 256) * E_NUM + e;
    float acc = 0.f;
#pragma unroll 4
    for (int i = 0; i < 256; ++i) acc += xp[i] * rp[i * E_NUM];
    acc += __shfl_xor(acc, 16);
    acc += __shfl_xor(acc, 32);

    float lg[E_NUM], bi[E_NUM];
#pragma unroll
    for (int j = 0; j < E_NUM; ++j) {
        lg[j] = __shfl(acc, j);
        bi[j] = lg[j] + rbias[j];
    }
    bool used[E_NUM];
#pragma unroll
    for (int j = 0; j < E_NUM; ++j) used[j] = false;
    int selv[K_TOP]; float wvv[K_TOP]; float wsum = 0.f;
#pragma unroll
    for (int k = 0; k < K_TOP; ++k) {
        float best = -1e30f; int bidx = 0;
#pragma unroll
        for (int j = 0; j < E_NUM; ++j)
            if (!used[j] && bi[j] > best) { best = bi[j]; bidx = j; }
#pragma unroll
        for (int j = 0; j < E_NUM; ++j) if (j == bidx) used[j] = true;
        selv[k] = bidx;
        float lgv = 0.f;
#pragma unroll
        for (int j = 0; j < E_NUM; ++j) if (j == bidx) lgv = lg[j];
        const float s = 1.f / (1.f + expf(-lgv));
        wvv[k] = s; wsum += s;
    }
    if (lane == 0) {
#pragma unroll
        for (int k = 0; k < K_TOP; ++k) {
            sel_idx[t * K_TOP + k] = selv[k];
            sel_w[t * K_TOP + k] = wvv[k] / wsum;
            atomicAdd(&counts[selv[k]], 1);
        }
    }
}

// ---------------- prefix scan + counts/entropy -----------------
__global__ void scan_stats_kernel(const int* __restrict__ counts,
                                  int* __restrict__ offsets, int* __restrict__ cursor,
                                  float* __restrict__ out_tail)
{
    if (threadIdx.x == 0 && blockIdx.x == 0) {
        int off = 0; float tot = 0.f;
        for (int e = 0; e < E_NUM; ++e) {
            offsets[e] = off; cursor[e] = off; off += counts[e];
            tot += (float)counts[e];
        }
        offsets[E_NUM] = off;
        const float total = fmaxf(tot, 1.f);
        float ent = 0.f;
        for (int e = 0; e < E_NUM; ++e) {
            const float c = (float)counts[e];
            const float frac = c / total;
            ent -= frac * logf(frac + 1e-6f);
            out_tail[e] = c;
        }
        out_tail[E_NUM] = ent;
    }
}

// ---------------- expert-grouped permutation -----------------
__global__ void scatter_kernel(const int* __restrict__ sel_idx,
                               int* __restrict__ cursor, int* __restrict__ perm)
{
    const int i = blockIdx.x * 256 + threadIdx.x;
    if (i >= T_TOK * K_TOP) return;
    const int e = sel_idx[i];
    const int pos = atomicAdd(&cursor[e], 1);
    perm[pos] = i;
}

// ---------------- x fp32 -> bf16 -----------------
__global__ __launch_bounds__(256) void convert_x_kernel(
    const float* __restrict__ x, __bf16* __restrict__ xb)
{
    const int i = blockIdx.x * 256 + threadIdx.x;   // 8 elems per thread
    const float4 a = reinterpret_cast<const float4*>(x)[i * 2];
    const float4 b = reinterpret_cast<const float4*>(x)[i * 2 + 1];
    bf16x8 o;
    o[0] = (__bf16)a.x; o[1] = (__bf16)a.y; o[2] = (__bf16)a.z; o[3] = (__bf16)a.w;
    o[4] = (__bf16)b.x; o[5] = (__bf16)b.y; o[6] = (__bf16)b.z; o[7] = (__bf16)b.w;
    reinterpret_cast<bf16x8*>(xb)[i] = o;
}

// ---------------- weight transpose fp32 [e][R][C] -> bf16 [e][C][R] ----------
__global__ __launch_bounds__(256) void transpose_w_kernel(
    const float* __restrict__ in, __bf16* __restrict__ out, int R, int C)
{
    const int e = blockIdx.z;
    const int r0 = blockIdx.y * 32, c0 = blockIdx.x * 32;
    const int tid = threadIdx.x;
    const int r = tid >> 3, c4 = (tid & 7) * 4;
    __shared__ float lds[32][33];
    const float4 v = *reinterpret_cast<const float4*>(
        in + (size_t)e * R * C + (size_t)(r0 + r) * C + c0 + c4);
    lds[c4 + 0][r] = v.x; lds[c4 + 1][r] = v.y;
    lds[c4 + 2][r] = v.z; lds[c4 + 3][r] = v.w;
    __syncthreads();
    bf16x4 o;
    o[0] = (__bf16)lds[r][c4 + 0]; o[1] = (__bf16)lds[r][c4 + 1];
    o[2] = (__bf16)lds[r][c4 + 2]; o[3] = (__bf16)lds[r][c4 + 3];
    *reinterpret_cast<bf16x4*>(out + (size_t)e * R * C + (size_t)(c0 + r) * R + r0 + c4) = o;
}

// ---------------- gate/up MFMA GEMM: 128 rows x (64 g + 64 u cols) -----------
__global__ __launch_bounds__(256) void gate_mfma_kernel(
    const __bf16* __restrict__ xb, const __bf16* __restrict__ wguT,
    const int* __restrict__ offsets, const int* __restrict__ perm,
    const float* __restrict__ sel_w, __bf16* __restrict__ h)
{
    const int e = blockIdx.z;
    const int base = offsets[e];
    const int nrows = offsets[e + 1] - base;
    const int m0 = blockIdx.y * 128;
    if (m0 >= nrows) return;
    const int c0 = blockIdx.x * 64;           // g-col tile (0..511)

    __shared__ __align__(16) __bf16 As[128 * 32];
    __shared__ __align__(16) __bf16 Bg[64 * 32];
    __shared__ __align__(16) __bf16 Bu[64 * 32];
    __shared__ int   tokrow[128];
    __shared__ float wrow[128];

    const int tid = threadIdx.x;
    const int wv = tid >> 6, lane = tid & 63;

    if (tid < 128) {
        const int gr = m0 + tid;
        const int grc = min(gr, nrows - 1);
        const int pv = perm[base + grc];
        tokrow[tid] = pv >> 2;
        wrow[tid] = (gr < nrows) ? sel_w[pv] : 0.f;
    }
    __syncthreads();

    // staging: A = 512 chunks of 16B (8 bf16), B tiles 256 chunks each
    const int ca0 = wv * 64 + lane, ca1 = 256 + wv * 64 + lane;
    const int ra0 = ca0 >> 2, ka0 = (ca0 & 3) ^ (ra0 & 3);
    const int ra1 = ca1 >> 2, ka1 = (ca1 & 3) ^ (ra1 & 3);
    const __bf16* a_src0 = xb + (size_t)tokrow[ra0] * D_DIM + ka0 * 8;
    const __bf16* a_src1 = xb + (size_t)tokrow[ra1] * D_DIM + ka1 * 8;
    const int cb = wv * 64 + lane;
    const int rb = cb >> 2, kb = (cb & 3) ^ (rb & 3);
    const size_t wbase = (size_t)e * D_DIM * TWOI;
    const __bf16* bg_src = wguT + wbase + (size_t)(c0 + rb) * D_DIM + kb * 8;
    const __bf16* bu_src = wguT + wbase + (size_t)(c0 + 512 + rb) * D_DIM + kb * 8;
    __bf16* a_dst0 = As + wv * 512;
    __bf16* a_dst1 = As + 2048 + wv * 512;
    __bf16* bg_dst = Bg + wv * 512;
    __bf16* bu_dst = Bu + wv * 512;

    const int wr = wv >> 1, wc = wv & 1;
    int a_off[4], b_off[2];
#pragma unroll
    for (int m = 0; m < 4; ++m) {
        const int row = wr * 64 + m * 16 + (lane & 15);
        a_off[m] = row * 32 + (((lane >> 4) ^ (row & 3)) << 3);
    }
#pragma unroll
    for (int n = 0; n < 2; ++n) {
        const int col = wc * 32 + n * 16 + (lane & 15);
        b_off[n] = col * 32 + (((lane >> 4) ^ (col & 3)) << 3);
    }

    f32x4 accg[4][2] = {}; f32x4 accu[4][2] = {};
    for (int d0 = 0; d0 < D_DIM; d0 += 32) {
        gload_lds16(a_src0 + d0, a_dst0);
        gload_lds16(a_src1 + d0, a_dst1);
        gload_lds16(bg_src + d0, bg_dst);
        gload_lds16(bu_src + d0, bu_dst);
        __syncthreads();
        bf16x8 af[4], bgf[2], buf[2];
#pragma unroll
        for (int m = 0; m < 4; ++m) af[m] = *reinterpret_cast<const bf16x8*>(&As[a_off[m]]);
#pragma unroll
        for (int n = 0; n < 2; ++n) {
            bgf[n] = *reinterpret_cast<const bf16x8*>(&Bg[b_off[n]]);
            buf[n] = *reinterpret_cast<const bf16x8*>(&Bu[b_off[n]]);
        }
#pragma unroll
        for (int m = 0; m < 4; ++m)
#pragma unroll
            for (int n = 0; n < 2; ++n) {
                accg[m][n] = __builtin_amdgcn_mfma_f32_16x16x32_bf16(af[m], bgf[n], accg[m][n], 0, 0, 0);
                accu[m][n] = __builtin_amdgcn_mfma_f32_16x16x32_bf16(af[m], buf[n], accu[m][n], 0, 0, 0);
            }
        __syncthreads();
    }

#pragma unroll
    for (int m = 0; m < 4; ++m)
#pragma unroll
        for (int n = 0; n < 2; ++n)
#pragma unroll
            for (int j = 0; j < 4; ++j) {
                const int lr = wr * 64 + m * 16 + (lane >> 4) * 4 + j;
                const int gr = m0 + lr;
                if (gr < nrows) {
                    const int col = c0 + wc * 32 + n * 16 + (lane & 15);
                    const float g = accg[m][n][j];
                    const float u = accu[m][n][j];
                    const float s = g / (1.f + expf(-g));
                    h[(size_t)(base + gr) * I_DIM + col] = (__bf16)(s * u * wrow[lr]);
                }
            }
}

// ---------------- down MFMA GEMM: 128 rows x 128 cols, atomic scatter --------
__global__ __launch_bounds__(256) void down_mfma_kernel(
    const __bf16* __restrict__ h, const __bf16* __restrict__ wdnT,
    const int* __restrict__ offsets, const int* __restrict__ perm,
    float* __restrict__ y)
{
    const int e = blockIdx.z;
    const int base = offsets[e];
    const int nrows = offsets[e + 1] - base;
    const int m0 = blockIdx.y * 128;
    if (m0 >= nrows) return;
    const int c0 = blockIdx.x * 128;

    __shared__ __align__(16) __bf16 As[128 * 32];
    __shared__ __align__(16) __bf16 Bs[128 * 32];
    __shared__ int tokrow[128];

    const int tid = threadIdx.x;
    const int wv = tid >> 6, lane = tid & 63;

    if (tid < 128) {
        const int gr = m0 + tid;
        const int grc = min(gr, nrows - 1);
        tokrow[tid] = perm[base + grc] >> 2;
    }
    __syncthreads();

    const int ca0 = wv * 64 + lane, ca1 = 256 + wv * 64 + lane;
    const int ra0 = ca0 >> 2, ka0 = (ca0 & 3) ^ (ra0 & 3);
    const int ra1 = ca1 >> 2, ka1 = (ca1 & 3) ^ (ra1 & 3);
    const __bf16* a_src0 = h + (size_t)(base + min(m0 + ra0, nrows - 1)) * I_DIM + ka0 * 8;
    const __bf16* a_src1 = h + (size_t)(base + min(m0 + ra1, nrows - 1)) * I_DIM + ka1 * 8;
    const size_t wbase = (size_t)e * I_DIM * D_DIM;
    const __bf16* b_src0 = wdnT + wbase + (size_t)(c0 + ra0) * I_DIM + ka0 * 8;
    const __bf16* b_src1 = wdnT + wbase + (size_t)(c0 + ra1) * I_DIM + ka1 * 8;
    __bf16* a_dst0 = As + wv * 512;
    __bf16* a_dst1 = As + 2048 + wv * 512;
    __bf16* b_dst0 = Bs + wv * 512;
    __bf16* b_dst1 = Bs + 2048 + wv * 512;

    const int wr = wv >> 1, wc = wv & 1;
    int a_off[4], b_off[4];
#pragma unroll
    for (int m = 0; m < 4; ++m) {
        const int row = wr * 64 + m * 16 + (lane & 15);
        a_off[m] = row * 32 + (((lane >> 4) ^ (row & 3)) << 3);
        const int col = wc * 64 + m * 16 + (lane & 15);
        b_off[m] = col * 32 + (((lane >> 4) ^ (col & 3)) << 3);
    }

    f32x4 acc[4][4] = {};
    for (int d0 = 0; d0 < I_DIM; d0 += 32) {
        gload_lds16(a_src0 + d0, a_dst0);
        gload_lds16(a_src1 + d0, a_dst1);
        gload_lds16(b_src0 + d0, b_dst0);
        gload_lds16(b_src1 + d0, b_dst1);
        __syncthreads();
        bf16x8 af[4], bf[4];
#pragma unroll
        for (int m = 0; m < 4; ++m) {
            af[m] = *reinterpret_cast<const bf16x8*>(&As[a_off[m]]);
            bf[m] = *reinterpret_cast<const bf16x8*>(&Bs[b_off[m]]);
        }
#pragma unroll
        for (int m = 0; m < 4; ++m)
#pragma unroll
            for (int n = 0; n < 4; ++n)
                acc[m][n] = __builtin_amdgcn_mfma_f32_16x16x32_bf16(af[m], bf[n], acc[m][n], 0, 0, 0);
        __syncthreads();
    }

#pragma unroll
    for (int m = 0; m < 4; ++m)
#pragma unroll
        for (int j = 0; j < 4; ++j) {
            const int lr = wr * 64 + m * 16 + (lane >> 4) * 4 + j;
            const int gr = m0 + lr;
            if (gr < nrows) {
                const int tok = tokrow[lr];
#pragma unroll
                for (int n = 0; n < 4; ++n) {
                    const int col = c0 + wc * 64 + n * 16 + (lane & 15);
                    atomicAdd(&y[(size_t)tok * D_DIM + col], acc[m][n][j]);
                }
            }
        }
}

// ================= fallback fp32 path (round-0, proven) ======================
__global__ __launch_bounds__(256) void gate_gemm_kernel(
    const float* __restrict__ x, const float* __restrict__ wgu,
    const int* __restrict__ offsets, const int* __restrict__ perm,
    const float* __restrict__ sel_w, float* __restrict__ h)
{
    const int e = blockIdx.z;
    const int base = offsets[e];
    const int nrows = offsets[e + 1] - base;
    const int m0 = blockIdx.y * 64;
    if (m0 >= nrows) return;
    const int c0 = blockIdx.x * 64;
    const int tid = threadIdx.x;
    __shared__ float As[16][64];
    __shared__ float Bg[16][64];
    __shared__ float Bu[16][64];
    const int lrow = tid >> 2;
    const int c4 = (tid & 3) * 4;
    const int grow = m0 + lrow;
    const bool arow_ok = (grow < nrows);
    const float* xrow = nullptr;
    if (arow_ok) {
        const int pv = perm[base + grow];
        xrow = x + (size_t)(pv >> 2) * D_DIM;
    }
    const int bcol = tid & 63;
    const int brow0 = tid >> 6;
    const float* wbase = wgu + (size_t)e * D_DIM * TWOI;
    const int tx = tid & 15, ty = tid >> 4;
    float accg[4][4] = {}, accu[4][4] = {};
    for (int d0 = 0; d0 < D_DIM; d0 += 16) {
        float4 av = make_float4(0.f, 0.f, 0.f, 0.f);
        if (arow_ok) av = *reinterpret_cast<const float4*>(xrow + d0 + c4);
        As[c4 + 0][lrow] = av.x; As[c4 + 1][lrow] = av.y;
        As[c4 + 2][lrow] = av.z; As[c4 + 3][lrow] = av.w;
#pragma unroll
        for (int r = 0; r < 4; ++r) {
            const int dd = d0 + brow0 + r * 4;
            const float* wr = wbase + (size_t)dd * TWOI;
            Bg[brow0 + r * 4][bcol] = wr[c0 + bcol];
            Bu[brow0 + r * 4][bcol] = wr[c0 + 512 + bcol];
        }
        __syncthreads();
#pragma unroll
        for (int kk = 0; kk < 16; ++kk) {
            const float4 a  = *reinterpret_cast<const float4*>(&As[kk][ty * 4]);
            const float4 bg = *reinterpret_cast<const float4*>(&Bg[kk][tx * 4]);
            const float4 bu = *reinterpret_cast<const float4*>(&Bu[kk][tx * 4]);
            const float aa[4] = { a.x, a.y, a.z, a.w };
            const float gg[4] = { bg.x, bg.y, bg.z, bg.w };
            const float uu[4] = { bu.x, bu.y, bu.z, bu.w };
#pragma unroll
            for (int i2 = 0; i2 < 4; ++i2)
#pragma unroll
                for (int j = 0; j < 4; ++j) {
                    accg[i2][j] += aa[i2] * gg[j];
                    accu[i2][j] += aa[i2] * uu[j];
                }
        }
        __syncthreads();
    }
#pragma unroll
    for (int i2 = 0; i2 < 4; ++i2) {
        const int r = ty * 4 + i2;
        const int gr = m0 + r;
        if (gr < nrows) {
            const int pv = perm[base + gr];
            const float wgt = sel_w[pv];
            float* hrow = h + (size_t)(base + gr) * I_DIM + c0;
#pragma unroll
            for (int j = 0; j < 4; ++j) {
                const float g = accg[i2][j];
                const float u = accu[i2][j];
                const float s = g / (1.f + expf(-g));
                hrow[tx * 4 + j] = s * u * wgt;
            }
        }
    }
}

__global__ __launch_bounds__(256) void down_gemm_kernel(
    const float* __restrict__ h, const float* __restrict__ wdn,
    const int* __restrict__ offsets, const int* __restrict__ perm,
    float* __restrict__ y)
{
    const int e = blockIdx.z;
    const int base = offsets[e];
    const int nrows = offsets[e + 1] - base;
    const int m0 = blockIdx.y * 64;
    if (m0 >= nrows) return;
    const int c0 = blockIdx.x * 64;
    const int tid = threadIdx.x;
    __shared__ float As[16][64];
    __shared__ float Bs[16][64];
    const int lrow = tid >> 2;
    const int c4 = (tid & 3) * 4;
    const int grow = m0 + lrow;
    const bool arow_ok = (grow < nrows);
    const float* hrow = arow_ok ? (h + (size_t)(base + grow) * I_DIM) : nullptr;
    const int bcol = tid & 63;
    const int brow0 = tid >> 6;
    const float* wbase = wdn + (size_t)e * I_DIM * D_DIM;
    const int tx = tid & 15, ty = tid >> 4;
    float acc[4][4] = {};
    for (int d0 = 0; d0 < I_DIM; d0 += 16) {
        float4 av = make_float4(0.f, 0.f, 0.f, 0.f);
        if (arow_ok) av = *reinterpret_cast<const float4*>(hrow + d0 + c4);
        As[c4 + 0][lrow] = av.x; As[c4 + 1][lrow] = av.y;
        As[c4 + 2][lrow] = av.z; As[c4 + 3][lrow] = av.w;
#pragma unroll
        for (int r = 0; r < 4; ++r) {
            const int dd = d0 + brow0 + r * 4;
            Bs[brow0 + r * 4][bcol] = wbase[(size_t)dd * D_DIM + c0 + bcol];
        }
        __syncthreads();
#pragma unroll
        for (int kk = 0; kk < 16; ++kk) {
            const float4 a = *reinterpret_cast<const float4*>(&As[kk][ty * 4]);
            const float4 b = *reinterpret_cast<const float4*>(&Bs[kk][tx * 4]);
            const float aa[4] = { a.x, a.y, a.z, a.w };
            const float bb[4] = { b.x, b.y, b.z, b.w };
#pragma unroll
            for (int i2 = 0; i2 < 4; ++i2)
#pragma unroll
                for (int j = 0; j < 4; ++j)
                    acc[i2][j] += aa[i2] * bb[j];
        }
        __syncthreads();
    }
#pragma unroll
    for (int i2 = 0; i2 < 4; ++i2) {
        const int r = ty * 4 + i2;
        const int gr = m0 + r;
        if (gr < nrows) {
            const int pv = perm[base + gr];
            const int t = pv >> 2;
            float* yrow = y + (size_t)t * D_DIM + c0;
#pragma unroll
            for (int j = 0; j < 4; ++j)
                atomicAdd(&yrow[tx * 4 + j], acc[i2][j]);
        }
    }
}

// ---------------- launch -----------------------------------------------------
extern "C" void kernel_launch(void* const* d_in, const int* in_sizes, int n_in,
                              void* d_out, int out_size, void* d_ws, size_t ws_size,
                              hipStream_t stream)
{
    const float* x      = (const float*)d_in[0];
    const float* router = (const float*)d_in[1];
    const float* rbias  = (const float*)d_in[2];
    const float* wgu    = (const float*)d_in[3];
    const float* wdn    = (const float*)d_in[4];
    float* out = (float*)d_out;

    char* ws = (char*)d_ws;
    int*   sel_idx = (int*)(ws);                    // 32 KB
    float* sel_w   = (float*)(ws + 32768);          // 32 KB
    int*   perm    = (int*)(ws + 65536);            // 32 KB
    int*   counts  = (int*)(ws + 98304);
    int*   offsets = (int*)(ws + 98560);
    int*   cursor  = (int*)(ws + 98816);
    __bf16* xb   = (__bf16*)(ws + 131072);          // 4 MB
    __bf16* hb   = (__bf16*)(ws + 4325376);         // 8 MB
    __bf16* wguT = (__bf16*)(ws + 12713984);        // 32 MB
    __bf16* wdnT = (__bf16*)(ws + 46268416);        // 16 MB, end 63045632
    float* hf    = (float*)(ws + 131072);           // fallback fp32 h (16.8 MB)

    const bool fast = (ws_size >= 63045632ULL);

    hipMemsetAsync(counts, 0, 64, stream);
    hipMemsetAsync(out, 0, (size_t)T_TOK * D_DIM * sizeof(float), stream);

    router_wave_kernel<<<T_TOK / 4, 256, 0, stream>>>(x, router, rbias, sel_idx, sel_w, counts);
    scan_stats_kernel<<<1, 64, 0, stream>>>(counts, offsets, cursor,
                                            out + (size_t)T_TOK * D_DIM);
    scatter_kernel<<<(T_TOK * K_TOP + 255) / 256, 256, 0, stream>>>(sel_idx, cursor, perm);

    if (fast) {
        convert_x_kernel<<<T_TOK * D_DIM / 8 / 256, 256, 0, stream>>>(x, xb);
        transpose_w_kernel<<<dim3(TWOI / 32, D_DIM / 32, E_NUM), 256, 0, stream>>>(wgu, wguT, D_DIM, TWOI);
        transpose_w_kernel<<<dim3(D_DIM / 32, I_DIM / 32, E_NUM), 256, 0, stream>>>(wdn, wdnT, I_DIM, D_DIM);
        gate_mfma_kernel<<<dim3(8, 16, E_NUM), 256, 0, stream>>>(xb, wguT, offsets, perm, sel_w, hb);
        down_mfma_kernel<<<dim3(8, 16, E_NUM), 256, 0, stream>>>(hb, wdnT, offsets, perm, out);
    } else {
        gate_gemm_kernel<<<dim3(8, 32, E_NUM), 256, 0, stream>>>(x, wgu, offsets, perm, sel_w, hf);
        down_gemm_kernel<<<dim3(16, 32, E_NUM), 256, 0, stream>>>(hf, wdn, offsets, perm, out);
    }
}

// Round 5
// 297.475 us; speedup vs baseline: 2.3195x; 1.2547x over previous
//
#include <hip/hip_runtime.h>
#include <hip/hip_bf16.h>
#include <cstdint>

#define T_TOK 2048
#define D_DIM 1024
#define E_NUM 16
#define K_TOP 4
#define I_DIM 512
#define TWOI  1024
#define RTPB  8

typedef __bf16 bf16x8 __attribute__((ext_vector_type(8)));
typedef __bf16 bf16x4 __attribute__((ext_vector_type(4)));
typedef float  f32x4  __attribute__((ext_vector_type(4)));

__device__ __forceinline__ void gload_lds16(const void* g, void* l) {
    __builtin_amdgcn_global_load_lds(
        (const __attribute__((address_space(1))) void*)(uintptr_t)(g),
        (__attribute__((address_space(3))) void*)(uintptr_t)(l),
        16, 0, 0);
}

// ---------------- router transpose: [d][e] -> [e][d] (64 KB) -----------------
__global__ __launch_bounds__(256) void transpose_router_kernel(
    const float* __restrict__ router, float* __restrict__ routerT)
{
    const int i = blockIdx.x * 256 + threadIdx.x;   // 16384 elements
    const int e = i & 15, d = i >> 4;
    routerT[(size_t)e * D_DIM + d] = router[i];     // coalesced read, scatter write
}

// ---------------- fast router: 8 tokens/block, fp32 exact --------------------
__global__ __launch_bounds__(256) void router_fast_kernel(
    const float* __restrict__ x, const float* __restrict__ routerT,
    const float* __restrict__ rbias,
    int* __restrict__ sel_idx, float* __restrict__ sel_w, int* __restrict__ counts)
{
    __shared__ float4 xs[RTPB * 256];     // 8 rows x 1024 floats
    __shared__ float lgs[RTPB][E_NUM];
    const int tid = threadIdx.x;
    const int t0 = blockIdx.x * RTPB;

    const float4* xg = reinterpret_cast<const float4*>(x + (size_t)t0 * D_DIM);
#pragma unroll
    for (int j = 0; j < RTPB; ++j) xs[tid + j * 256] = xg[tid + j * 256];
    __syncthreads();

    const int tok = tid >> 5, sub = tid & 31, half = sub >> 4, e = sub & 15;
    const float4* xr = xs + tok * 256 + half * 128;
    const float4* rr = reinterpret_cast<const float4*>(routerT + (size_t)e * D_DIM) + half * 128;
    float4 a = make_float4(0.f, 0.f, 0.f, 0.f);
#pragma unroll 8
    for (int i = 0; i < 128; ++i) {
        const float4 xv = xr[i], rv = rr[i];
        a.x += xv.x * rv.x; a.y += xv.y * rv.y;
        a.z += xv.z * rv.z; a.w += xv.w * rv.w;
    }
    float acc = (a.x + a.y) + (a.z + a.w);
    acc += __shfl_xor(acc, 16);           // merge D-halves (tid bit 4)
    if (half == 0) lgs[tok][e] = acc;
    __syncthreads();

    if (tid < RTPB) {
        const int t = t0 + tid;
        float lg[E_NUM], bi[E_NUM];
#pragma unroll
        for (int j = 0; j < E_NUM; ++j) { lg[j] = lgs[tid][j]; bi[j] = lg[j] + rbias[j]; }
        bool used[E_NUM];
#pragma unroll
        for (int j = 0; j < E_NUM; ++j) used[j] = false;
        int selv[K_TOP]; float wvv[K_TOP]; float wsum = 0.f;
#pragma unroll
        for (int k = 0; k < K_TOP; ++k) {
            float best = -1e30f; int bidx = 0;
#pragma unroll
            for (int j = 0; j < E_NUM; ++j)
                if (!used[j] && bi[j] > best) { best = bi[j]; bidx = j; }
            used[bidx] = true; selv[k] = bidx;
            const float s = 1.f / (1.f + expf(-lg[bidx]));
            wvv[k] = s; wsum += s;
        }
#pragma unroll
        for (int k = 0; k < K_TOP; ++k) {
            sel_idx[t * K_TOP + k] = selv[k];
            sel_w[t * K_TOP + k] = wvv[k] / wsum;
            atomicAdd(&counts[selv[k]], 1);
        }
    }
}

// ---------------- fallback router (round-1 proven, latency-bound) ------------
__global__ __launch_bounds__(256) void router_wave_kernel(
    const float* __restrict__ x, const float* __restrict__ router,
    const float* __restrict__ rbias,
    int* __restrict__ sel_idx, float* __restrict__ sel_w, int* __restrict__ counts)
{
    const int wv = threadIdx.x >> 6;
    const int lane = threadIdx.x & 63;
    const int t = blockIdx.x * 4 + wv;
    if (t >= T_TOK) return;
    const int e = lane & 15, dg = lane >> 4;

    const float* xp = x + (size_t)t * D_DIM + dg * 256;
    const float* rp = router + (size_t)(dg * 256) * E_NUM + e;
    float acc = 0.f;
#pragma unroll 4
    for (int i = 0; i < 256; ++i) acc += xp[i] * rp[i * E_NUM];
    acc += __shfl_xor(acc, 16);
    acc += __shfl_xor(acc, 32);

    float lg[E_NUM], bi[E_NUM];
#pragma unroll
    for (int j = 0; j < E_NUM; ++j) {
        lg[j] = __shfl(acc, j);
        bi[j] = lg[j] + rbias[j];
    }
    bool used[E_NUM];
#pragma unroll
    for (int j = 0; j < E_NUM; ++j) used[j] = false;
    int selv[K_TOP]; float wvv[K_TOP]; float wsum = 0.f;
#pragma unroll
    for (int k = 0; k < K_TOP; ++k) {
        float best = -1e30f; int bidx = 0;
#pragma unroll
        for (int j = 0; j < E_NUM; ++j)
            if (!used[j] && bi[j] > best) { best = bi[j]; bidx = j; }
#pragma unroll
        for (int j = 0; j < E_NUM; ++j) if (j == bidx) used[j] = true;
        selv[k] = bidx;
        float lgv = 0.f;
#pragma unroll
        for (int j = 0; j < E_NUM; ++j) if (j == bidx) lgv = lg[j];
        const float s = 1.f / (1.f + expf(-lgv));
        wvv[k] = s; wsum += s;
    }
    if (lane == 0) {
#pragma unroll
        for (int k = 0; k < K_TOP; ++k) {
            sel_idx[t * K_TOP + k] = selv[k];
            sel_w[t * K_TOP + k] = wvv[k] / wsum;
            atomicAdd(&counts[selv[k]], 1);
        }
    }
}

// ---------------- prefix scan + counts/entropy -----------------
__global__ void scan_stats_kernel(const int* __restrict__ counts,
                                  int* __restrict__ offsets, int* __restrict__ cursor,
                                  float* __restrict__ out_tail)
{
    if (threadIdx.x == 0 && blockIdx.x == 0) {
        int off = 0; float tot = 0.f;
        for (int e = 0; e < E_NUM; ++e) {
            offsets[e] = off; cursor[e] = off; off += counts[e];
            tot += (float)counts[e];
        }
        offsets[E_NUM] = off;
        const float total = fmaxf(tot, 1.f);
        float ent = 0.f;
        for (int e = 0; e < E_NUM; ++e) {
            const float c = (float)counts[e];
            const float frac = c / total;
            ent -= frac * logf(frac + 1e-6f);
            out_tail[e] = c;
        }
        out_tail[E_NUM] = ent;
    }
}

// ---------------- expert-grouped permutation -----------------
__global__ void scatter_kernel(const int* __restrict__ sel_idx,
                               int* __restrict__ cursor, int* __restrict__ perm)
{
    const int i = blockIdx.x * 256 + threadIdx.x;
    if (i >= T_TOK * K_TOP) return;
    const int e = sel_idx[i];
    const int pos = atomicAdd(&cursor[e], 1);
    perm[pos] = i;
}

// ---------------- x fp32 -> bf16 -----------------
__global__ __launch_bounds__(256) void convert_x_kernel(
    const float* __restrict__ x, __bf16* __restrict__ xb)
{
    const int i = blockIdx.x * 256 + threadIdx.x;   // 8 elems per thread
    const float4 a = reinterpret_cast<const float4*>(x)[i * 2];
    const float4 b = reinterpret_cast<const float4*>(x)[i * 2 + 1];
    bf16x8 o;
    o[0] = (__bf16)a.x; o[1] = (__bf16)a.y; o[2] = (__bf16)a.z; o[3] = (__bf16)a.w;
    o[4] = (__bf16)b.x; o[5] = (__bf16)b.y; o[6] = (__bf16)b.z; o[7] = (__bf16)b.w;
    reinterpret_cast<bf16x8*>(xb)[i] = o;
}

// ---------------- weight transpose fp32 [e][R][C] -> bf16 [e][C][R] ----------
__global__ __launch_bounds__(256) void transpose_w_kernel(
    const float* __restrict__ in, __bf16* __restrict__ out, int R, int C)
{
    const int e = blockIdx.z;
    const int r0 = blockIdx.y * 32, c0 = blockIdx.x * 32;
    const int tid = threadIdx.x;
    const int r = tid >> 3, c4 = (tid & 7) * 4;
    __shared__ float lds[32][33];
    const float4 v = *reinterpret_cast<const float4*>(
        in + (size_t)e * R * C + (size_t)(r0 + r) * C + c0 + c4);
    lds[c4 + 0][r] = v.x; lds[c4 + 1][r] = v.y;
    lds[c4 + 2][r] = v.z; lds[c4 + 3][r] = v.w;
    __syncthreads();
    bf16x4 o;
    o[0] = (__bf16)lds[r][c4 + 0]; o[1] = (__bf16)lds[r][c4 + 1];
    o[2] = (__bf16)lds[r][c4 + 2]; o[3] = (__bf16)lds[r][c4 + 3];
    *reinterpret_cast<bf16x4*>(out + (size_t)e * R * C + (size_t)(c0 + r) * R + r0 + c4) = o;
}

// ---------------- gate/up MFMA GEMM: 128 rows x (64 g + 64 u cols) -----------
__global__ __launch_bounds__(256) void gate_mfma_kernel(
    const __bf16* __restrict__ xb, const __bf16* __restrict__ wguT,
    const int* __restrict__ offsets, const int* __restrict__ perm,
    const float* __restrict__ sel_w, __bf16* __restrict__ h)
{
    const int e = blockIdx.z;
    const int base = offsets[e];
    const int nrows = offsets[e + 1] - base;
    const int m0 = blockIdx.y * 128;
    if (m0 >= nrows) return;
    const int c0 = blockIdx.x * 64;           // g-col tile (0..511)

    __shared__ __align__(16) __bf16 As[128 * 32];
    __shared__ __align__(16) __bf16 Bg[64 * 32];
    __shared__ __align__(16) __bf16 Bu[64 * 32];
    __shared__ int   tokrow[128];
    __shared__ float wrow[128];

    const int tid = threadIdx.x;
    const int wv = tid >> 6, lane = tid & 63;

    if (tid < 128) {
        const int gr = m0 + tid;
        const int grc = min(gr, nrows - 1);
        const int pv = perm[base + grc];
        tokrow[tid] = pv >> 2;
        wrow[tid] = (gr < nrows) ? sel_w[pv] : 0.f;
    }
    __syncthreads();

    // staging: A = 512 chunks of 16B (8 bf16), B tiles 256 chunks each
    const int ca0 = wv * 64 + lane, ca1 = 256 + wv * 64 + lane;
    const int ra0 = ca0 >> 2, ka0 = (ca0 & 3) ^ (ra0 & 3);
    const int ra1 = ca1 >> 2, ka1 = (ca1 & 3) ^ (ra1 & 3);
    const __bf16* a_src0 = xb + (size_t)tokrow[ra0] * D_DIM + ka0 * 8;
    const __bf16* a_src1 = xb + (size_t)tokrow[ra1] * D_DIM + ka1 * 8;
    const int cb = wv * 64 + lane;
    const int rb = cb >> 2, kb = (cb & 3) ^ (rb & 3);
    const size_t wbase = (size_t)e * D_DIM * TWOI;
    const __bf16* bg_src = wguT + wbase + (size_t)(c0 + rb) * D_DIM + kb * 8;
    const __bf16* bu_src = wguT + wbase + (size_t)(c0 + 512 + rb) * D_DIM + kb * 8;
    __bf16* a_dst0 = As + wv * 512;
    __bf16* a_dst1 = As + 2048 + wv * 512;
    __bf16* bg_dst = Bg + wv * 512;
    __bf16* bu_dst = Bu + wv * 512;

    const int wr = wv >> 1, wc = wv & 1;
    int a_off[4], b_off[2];
#pragma unroll
    for (int m = 0; m < 4; ++m) {
        const int row = wr * 64 + m * 16 + (lane & 15);
        a_off[m] = row * 32 + (((lane >> 4) ^ (row & 3)) << 3);
    }
#pragma unroll
    for (int n = 0; n < 2; ++n) {
        const int col = wc * 32 + n * 16 + (lane & 15);
        b_off[n] = col * 32 + (((lane >> 4) ^ (col & 3)) << 3);
    }

    f32x4 accg[4][2] = {}; f32x4 accu[4][2] = {};
    for (int d0 = 0; d0 < D_DIM; d0 += 32) {
        gload_lds16(a_src0 + d0, a_dst0);
        gload_lds16(a_src1 + d0, a_dst1);
        gload_lds16(bg_src + d0, bg_dst);
        gload_lds16(bu_src + d0, bu_dst);
        __syncthreads();
        bf16x8 af[4], bgf[2], buf[2];
#pragma unroll
        for (int m = 0; m < 4; ++m) af[m] = *reinterpret_cast<const bf16x8*>(&As[a_off[m]]);
#pragma unroll
        for (int n = 0; n < 2; ++n) {
            bgf[n] = *reinterpret_cast<const bf16x8*>(&Bg[b_off[n]]);
            buf[n] = *reinterpret_cast<const bf16x8*>(&Bu[b_off[n]]);
        }
#pragma unroll
        for (int m = 0; m < 4; ++m)
#pragma unroll
            for (int n = 0; n < 2; ++n) {
                accg[m][n] = __builtin_amdgcn_mfma_f32_16x16x32_bf16(af[m], bgf[n], accg[m][n], 0, 0, 0);
                accu[m][n] = __builtin_amdgcn_mfma_f32_16x16x32_bf16(af[m], buf[n], accu[m][n], 0, 0, 0);
            }
        __syncthreads();
    }

#pragma unroll
    for (int m = 0; m < 4; ++m)
#pragma unroll
        for (int n = 0; n < 2; ++n)
#pragma unroll
            for (int j = 0; j < 4; ++j) {
                const int lr = wr * 64 + m * 16 + (lane >> 4) * 4 + j;
                const int gr = m0 + lr;
                if (gr < nrows) {
                    const int col = c0 + wc * 32 + n * 16 + (lane & 15);
                    const float g = accg[m][n][j];
                    const float u = accu[m][n][j];
                    const float s = g / (1.f + expf(-g));
                    h[(size_t)(base + gr) * I_DIM + col] = (__bf16)(s * u * wrow[lr]);
                }
            }
}

// ---------------- down MFMA GEMM: 128 rows x 128 cols, atomic scatter --------
__global__ __launch_bounds__(256) void down_mfma_kernel(
    const __bf16* __restrict__ h, const __bf16* __restrict__ wdnT,
    const int* __restrict__ offsets, const int* __restrict__ perm,
    float* __restrict__ y)
{
    const int e = blockIdx.z;
    const int base = offsets[e];
    const int nrows = offsets[e + 1] - base;
    const int m0 = blockIdx.y * 128;
    if (m0 >= nrows) return;
    const int c0 = blockIdx.x * 128;

    __shared__ __align__(16) __bf16 As[128 * 32];
    __shared__ __align__(16) __bf16 Bs[128 * 32];
    __shared__ int tokrow[128];

    const int tid = threadIdx.x;
    const int wv = tid >> 6, lane = tid & 63;

    if (tid < 128) {
        const int gr = m0 + tid;
        const int grc = min(gr, nrows - 1);
        tokrow[tid] = perm[base + grc] >> 2;
    }
    __syncthreads();

    const int ca0 = wv * 64 + lane, ca1 = 256 + wv * 64 + lane;
    const int ra0 = ca0 >> 2, ka0 = (ca0 & 3) ^ (ra0 & 3);
    const int ra1 = ca1 >> 2, ka1 = (ca1 & 3) ^ (ra1 & 3);
    const __bf16* a_src0 = h + (size_t)(base + min(m0 + ra0, nrows - 1)) * I_DIM + ka0 * 8;
    const __bf16* a_src1 = h + (size_t)(base + min(m0 + ra1, nrows - 1)) * I_DIM + ka1 * 8;
    const size_t wbase = (size_t)e * I_DIM * D_DIM;
    const __bf16* b_src0 = wdnT + wbase + (size_t)(c0 + ra0) * I_DIM + ka0 * 8;
    const __bf16* b_src1 = wdnT + wbase + (size_t)(c0 + ra1) * I_DIM + ka1 * 8;
    __bf16* a_dst0 = As + wv * 512;
    __bf16* a_dst1 = As + 2048 + wv * 512;
    __bf16* b_dst0 = Bs + wv * 512;
    __bf16* b_dst1 = Bs + 2048 + wv * 512;

    const int wr = wv >> 1, wc = wv & 1;
    int a_off[4], b_off[4];
#pragma unroll
    for (int m = 0; m < 4; ++m) {
        const int row = wr * 64 + m * 16 + (lane & 15);
        a_off[m] = row * 32 + (((lane >> 4) ^ (row & 3)) << 3);
        const int col = wc * 64 + m * 16 + (lane & 15);
        b_off[m] = col * 32 + (((lane >> 4) ^ (col & 3)) << 3);
    }

    f32x4 acc[4][4] = {};
    for (int d0 = 0; d0 < I_DIM; d0 += 32) {
        gload_lds16(a_src0 + d0, a_dst0);
        gload_lds16(a_src1 + d0, a_dst1);
        gload_lds16(b_src0 + d0, b_dst0);
        gload_lds16(b_src1 + d0, b_dst1);
        __syncthreads();
        bf16x8 af[4], bf[4];
#pragma unroll
        for (int m = 0; m < 4; ++m) {
            af[m] = *reinterpret_cast<const bf16x8*>(&As[a_off[m]]);
            bf[m] = *reinterpret_cast<const bf16x8*>(&Bs[b_off[m]]);
        }
#pragma unroll
        for (int m = 0; m < 4; ++m)
#pragma unroll
            for (int n = 0; n < 4; ++n)
                acc[m][n] = __builtin_amdgcn_mfma_f32_16x16x32_bf16(af[m], bf[n], acc[m][n], 0, 0, 0);
        __syncthreads();
    }

#pragma unroll
    for (int m = 0; m < 4; ++m)
#pragma unroll
        for (int j = 0; j < 4; ++j) {
            const int lr = wr * 64 + m * 16 + (lane >> 4) * 4 + j;
            const int gr = m0 + lr;
            if (gr < nrows) {
                const int tok = tokrow[lr];
#pragma unroll
                for (int n = 0; n < 4; ++n) {
                    const int col = c0 + wc * 64 + n * 16 + (lane & 15);
                    atomicAdd(&y[(size_t)tok * D_DIM + col], acc[m][n][j]);
                }
            }
        }
}

// ================= fallback fp32 path (round-0, proven) ======================
__global__ __launch_bounds__(256) void gate_gemm_kernel(
    const float* __restrict__ x, const float* __restrict__ wgu,
    const int* __restrict__ offsets, const int* __restrict__ perm,
    const float* __restrict__ sel_w, float* __restrict__ h)
{
    const int e = blockIdx.z;
    const int base = offsets[e];
    const int nrows = offsets[e + 1] - base;
    const int m0 = blockIdx.y * 64;
    if (m0 >= nrows) return;
    const int c0 = blockIdx.x * 64;
    const int tid = threadIdx.x;
    __shared__ float As[16][64];
    __shared__ float Bg[16][64];
    __shared__ float Bu[16][64];
    const int lrow = tid >> 2;
    const int c4 = (tid & 3) * 4;
    const int grow = m0 + lrow;
    const bool arow_ok = (grow < nrows);
    const float* xrow = nullptr;
    if (arow_ok) {
        const int pv = perm[base + grow];
        xrow = x + (size_t)(pv >> 2) * D_DIM;
    }
    const int bcol = tid & 63;
    const int brow0 = tid >> 6;
    const float* wbase = wgu + (size_t)e * D_DIM * TWOI;
    const int tx = tid & 15, ty = tid >> 4;
    float accg[4][4] = {}, accu[4][4] = {};
    for (int d0 = 0; d0 < D_DIM; d0 += 16) {
        float4 av = make_float4(0.f, 0.f, 0.f, 0.f);
        if (arow_ok) av = *reinterpret_cast<const float4*>(xrow + d0 + c4);
        As[c4 + 0][lrow] = av.x; As[c4 + 1][lrow] = av.y;
        As[c4 + 2][lrow] = av.z; As[c4 + 3][lrow] = av.w;
#pragma unroll
        for (int r = 0; r < 4; ++r) {
            const int dd = d0 + brow0 + r * 4;
            const float* wr = wbase + (size_t)dd * TWOI;
            Bg[brow0 + r * 4][bcol] = wr[c0 + bcol];
            Bu[brow0 + r * 4][bcol] = wr[c0 + 512 + bcol];
        }
        __syncthreads();
#pragma unroll
        for (int kk = 0; kk < 16; ++kk) {
            const float4 a  = *reinterpret_cast<const float4*>(&As[kk][ty * 4]);
            const float4 bg = *reinterpret_cast<const float4*>(&Bg[kk][tx * 4]);
            const float4 bu = *reinterpret_cast<const float4*>(&Bu[kk][tx * 4]);
            const float aa[4] = { a.x, a.y, a.z, a.w };
            const float gg[4] = { bg.x, bg.y, bg.z, bg.w };
            const float uu[4] = { bu.x, bu.y, bu.z, bu.w };
#pragma unroll
            for (int i2 = 0; i2 < 4; ++i2)
#pragma unroll
                for (int j = 0; j < 4; ++j) {
                    accg[i2][j] += aa[i2] * gg[j];
                    accu[i2][j] += aa[i2] * uu[j];
                }
        }
        __syncthreads();
    }
#pragma unroll
    for (int i2 = 0; i2 < 4; ++i2) {
        const int r = ty * 4 + i2;
        const int gr = m0 + r;
        if (gr < nrows) {
            const int pv = perm[base + gr];
            const float wgt = sel_w[pv];
            float* hrow = h + (size_t)(base + gr) * I_DIM + c0;
#pragma unroll
            for (int j = 0; j < 4; ++j) {
                const float g = accg[i2][j];
                const float u = accu[i2][j];
                const float s = g / (1.f + expf(-g));
                hrow[tx * 4 + j] = s * u * wgt;
            }
        }
    }
}

__global__ __launch_bounds__(256) void down_gemm_kernel(
    const float* __restrict__ h, const float* __restrict__ wdn,
    const int* __restrict__ offsets, const int* __restrict__ perm,
    float* __restrict__ y)
{
    const int e = blockIdx.z;
    const int base = offsets[e];
    const int nrows = offsets[e + 1] - base;
    const int m0 = blockIdx.y * 64;
    if (m0 >= nrows) return;
    const int c0 = blockIdx.x * 64;
    const int tid = threadIdx.x;
    __shared__ float As[16][64];
    __shared__ float Bs[16][64];
    const int lrow = tid >> 2;
    const int c4 = (tid & 3) * 4;
    const int grow = m0 + lrow;
    const bool arow_ok = (grow < nrows);
    const float* hrow = arow_ok ? (h + (size_t)(base + grow) * I_DIM) : nullptr;
    const int bcol = tid & 63;
    const int brow0 = tid >> 6;
    const float* wbase = wdn + (size_t)e * I_DIM * D_DIM;
    const int tx = tid & 15, ty = tid >> 4;
    float acc[4][4] = {};
    for (int d0 = 0; d0 < I_DIM; d0 += 16) {
        float4 av = make_float4(0.f, 0.f, 0.f, 0.f);
        if (arow_ok) av = *reinterpret_cast<const float4*>(hrow + d0 + c4);
        As[c4 + 0][lrow] = av.x; As[c4 + 1][lrow] = av.y;
        As[c4 + 2][lrow] = av.z; As[c4 + 3][lrow] = av.w;
#pragma unroll
        for (int r = 0; r < 4; ++r) {
            const int dd = d0 + brow0 + r * 4;
            Bs[brow0 + r * 4][bcol] = wbase[(size_t)dd * D_DIM + c0 + bcol];
        }
        __syncthreads();
#pragma unroll
        for (int kk = 0; kk < 16; ++kk) {
            const float4 a = *reinterpret_cast<const float4*>(&As[kk][ty * 4]);
            const float4 b = *reinterpret_cast<const float4*>(&Bs[kk][tx * 4]);
            const float aa[4] = { a.x, a.y, a.z, a.w };
            const float bb[4] = { b.x, b.y, b.z, b.w };
#pragma unroll
            for (int i2 = 0; i2 < 4; ++i2)
#pragma unroll
                for (int j = 0; j < 4; ++j)
                    acc[i2][j] += aa[i2] * bb[j];
        }
        __syncthreads();
    }
#pragma unroll
    for (int i2 = 0; i2 < 4; ++i2) {
        const int r = ty * 4 + i2;
        const int gr = m0 + r;
        if (gr < nrows) {
            const int pv = perm[base + gr];
            const int t = pv >> 2;
            float* yrow = y + (size_t)t * D_DIM + c0;
#pragma unroll
            for (int j = 0; j < 4; ++j)
                atomicAdd(&yrow[tx * 4 + j], acc[i2][j]);
        }
    }
}

// ---------------- launch -----------------------------------------------------
extern "C" void kernel_launch(void* const* d_in, const int* in_sizes, int n_in,
                              void* d_out, int out_size, void* d_ws, size_t ws_size,
                              hipStream_t stream)
{
    const float* x      = (const float*)d_in[0];
    const float* router = (const float*)d_in[1];
    const float* rbias  = (const float*)d_in[2];
    const float* wgu    = (const float*)d_in[3];
    const float* wdn    = (const float*)d_in[4];
    float* out = (float*)d_out;

    char* ws = (char*)d_ws;
    int*   sel_idx = (int*)(ws);                    // 32 KB
    float* sel_w   = (float*)(ws + 32768);          // 32 KB
    int*   perm    = (int*)(ws + 65536);            // 32 KB
    int*   counts  = (int*)(ws + 98304);
    int*   offsets = (int*)(ws + 98560);
    int*   cursor  = (int*)(ws + 98816);
    __bf16* xb   = (__bf16*)(ws + 131072);          // 4 MB
    __bf16* hb   = (__bf16*)(ws + 4325376);         // 8 MB
    __bf16* wguT = (__bf16*)(ws + 12713984);        // 32 MB
    __bf16* wdnT = (__bf16*)(ws + 46268416);        // 16 MB
    float* routerT = (float*)(ws + 63045632);       // 64 KB, end 63111168
    float* hf    = (float*)(ws + 131072);           // fallback fp32 h (16.8 MB)

    const bool fast = (ws_size >= 63111168ULL);

    hipMemsetAsync(counts, 0, 64, stream);
    hipMemsetAsync(out, 0, (size_t)T_TOK * D_DIM * sizeof(float), stream);

    if (fast) {
        transpose_router_kernel<<<64, 256, 0, stream>>>(router, routerT);
        router_fast_kernel<<<T_TOK / RTPB, 256, 0, stream>>>(x, routerT, rbias, sel_idx, sel_w, counts);
    } else {
        router_wave_kernel<<<T_TOK / 4, 256, 0, stream>>>(x, router, rbias, sel_idx, sel_w, counts);
    }
    scan_stats_kernel<<<1, 64, 0, stream>>>(counts, offsets, cursor,
                                            out + (size_t)T_TOK * D_DIM);
    scatter_kernel<<<(T_TOK * K_TOP + 255) / 256, 256, 0, stream>>>(sel_idx, cursor, perm);

    if (fast) {
        convert_x_kernel<<<T_TOK * D_DIM / 8 / 256, 256, 0, stream>>>(x, xb);
        transpose_w_kernel<<<dim3(TWOI / 32, D_DIM / 32, E_NUM), 256, 0, stream>>>(wgu, wguT, D_DIM, TWOI);
        transpose_w_kernel<<<dim3(D_DIM / 32, I_DIM / 32, E_NUM), 256, 0, stream>>>(wdn, wdnT, I_DIM, D_DIM);
        gate_mfma_kernel<<<dim3(8, 16, E_NUM), 256, 0, stream>>>(xb, wguT, offsets, perm, sel_w, hb);
        down_mfma_kernel<<<dim3(8, 16, E_NUM), 256, 0, stream>>>(hb, wdnT, offsets, perm, out);
    } else {
        gate_gemm_kernel<<<dim3(8, 32, E_NUM), 256, 0, stream>>>(x, wgu, offsets, perm, sel_w, hf);
        down_gemm_kernel<<<dim3(16, 32, E_NUM), 256, 0, stream>>>(hf, wdn, offsets, perm, out);
    }
}

// Round 6
// 294.576 us; speedup vs baseline: 2.3424x; 1.0098x over previous
//
#include <hip/hip_runtime.h>
#include <hip/hip_bf16.h>
#include <cstdint>

#define T_TOK 2048
#define D_DIM 1024
#define E_NUM 16
#define K_TOP 4
#define I_DIM 512
#define TWOI  1024
#define RTPB  8

typedef __bf16 bf16x8 __attribute__((ext_vector_type(8)));
typedef __bf16 bf16x4 __attribute__((ext_vector_type(4)));
typedef float  f32x4  __attribute__((ext_vector_type(4)));

__device__ __forceinline__ void gload_lds16(const void* g, void* l) {
    __builtin_amdgcn_global_load_lds(
        (const __attribute__((address_space(1))) void*)(uintptr_t)(g),
        (__attribute__((address_space(3))) void*)(uintptr_t)(l),
        16, 0, 0);
}

// ---------------- router transpose: [d][e] -> [e][d] (64 KB) -----------------
__global__ __launch_bounds__(256) void transpose_router_kernel(
    const float* __restrict__ router, float* __restrict__ routerT)
{
    const int i = blockIdx.x * 256 + threadIdx.x;
    const int e = i & 15, d = i >> 4;
    routerT[(size_t)e * D_DIM + d] = router[i];
}

// ---------------- fast router: 8 tokens/block, fp32 exact --------------------
__global__ __launch_bounds__(256) void router_fast_kernel(
    const float* __restrict__ x, const float* __restrict__ routerT,
    const float* __restrict__ rbias,
    int* __restrict__ sel_idx, float* __restrict__ sel_w, int* __restrict__ counts)
{
    __shared__ float4 xs[RTPB * 256];
    __shared__ float lgs[RTPB][E_NUM];
    const int tid = threadIdx.x;
    const int t0 = blockIdx.x * RTPB;

    const float4* xg = reinterpret_cast<const float4*>(x + (size_t)t0 * D_DIM);
#pragma unroll
    for (int j = 0; j < RTPB; ++j) xs[tid + j * 256] = xg[tid + j * 256];
    __syncthreads();

    const int tok = tid >> 5, sub = tid & 31, half = sub >> 4, e = sub & 15;
    const float4* xr = xs + tok * 256 + half * 128;
    const float4* rr = reinterpret_cast<const float4*>(routerT + (size_t)e * D_DIM) + half * 128;
    float4 a = make_float4(0.f, 0.f, 0.f, 0.f);
#pragma unroll 8
    for (int i = 0; i < 128; ++i) {
        const float4 xv = xr[i], rv = rr[i];
        a.x += xv.x * rv.x; a.y += xv.y * rv.y;
        a.z += xv.z * rv.z; a.w += xv.w * rv.w;
    }
    float acc = (a.x + a.y) + (a.z + a.w);
    acc += __shfl_xor(acc, 16);
    if (half == 0) lgs[tok][e] = acc;
    __syncthreads();

    if (tid < RTPB) {
        const int t = t0 + tid;
        float lg[E_NUM], bi[E_NUM];
#pragma unroll
        for (int j = 0; j < E_NUM; ++j) { lg[j] = lgs[tid][j]; bi[j] = lg[j] + rbias[j]; }
        bool used[E_NUM];
#pragma unroll
        for (int j = 0; j < E_NUM; ++j) used[j] = false;
        int selv[K_TOP]; float wvv[K_TOP]; float wsum = 0.f;
#pragma unroll
        for (int k = 0; k < K_TOP; ++k) {
            float best = -1e30f; int bidx = 0;
#pragma unroll
            for (int j = 0; j < E_NUM; ++j)
                if (!used[j] && bi[j] > best) { best = bi[j]; bidx = j; }
            used[bidx] = true; selv[k] = bidx;
            const float s = 1.f / (1.f + expf(-lg[bidx]));
            wvv[k] = s; wsum += s;
        }
#pragma unroll
        for (int k = 0; k < K_TOP; ++k) {
            sel_idx[t * K_TOP + k] = selv[k];
            sel_w[t * K_TOP + k] = wvv[k] / wsum;
            atomicAdd(&counts[selv[k]], 1);
        }
    }
}

// ---------------- fallback router ------------
__global__ __launch_bounds__(256) void router_wave_kernel(
    const float* __restrict__ x, const float* __restrict__ router,
    const float* __restrict__ rbias,
    int* __restrict__ sel_idx, float* __restrict__ sel_w, int* __restrict__ counts)
{
    const int wv = threadIdx.x >> 6;
    const int lane = threadIdx.x & 63;
    const int t = blockIdx.x * 4 + wv;
    if (t >= T_TOK) return;
    const int e = lane & 15, dg = lane >> 4;

    const float* xp = x + (size_t)t * D_DIM + dg * 256;
    const float* rp = router + (size_t)(dg * 256) * E_NUM + e;
    float acc = 0.f;
#pragma unroll 4
    for (int i = 0; i < 256; ++i) acc += xp[i] * rp[i * E_NUM];
    acc += __shfl_xor(acc, 16);
    acc += __shfl_xor(acc, 32);

    float lg[E_NUM], bi[E_NUM];
#pragma unroll
    for (int j = 0; j < E_NUM; ++j) {
        lg[j] = __shfl(acc, j);
        bi[j] = lg[j] + rbias[j];
    }
    bool used[E_NUM];
#pragma unroll
    for (int j = 0; j < E_NUM; ++j) used[j] = false;
    int selv[K_TOP]; float wvv[K_TOP]; float wsum = 0.f;
#pragma unroll
    for (int k = 0; k < K_TOP; ++k) {
        float best = -1e30f; int bidx = 0;
#pragma unroll
        for (int j = 0; j < E_NUM; ++j)
            if (!used[j] && bi[j] > best) { best = bi[j]; bidx = j; }
#pragma unroll
        for (int j = 0; j < E_NUM; ++j) if (j == bidx) used[j] = true;
        selv[k] = bidx;
        float lgv = 0.f;
#pragma unroll
        for (int j = 0; j < E_NUM; ++j) if (j == bidx) lgv = lg[j];
        const float s = 1.f / (1.f + expf(-lgv));
        wvv[k] = s; wsum += s;
    }
    if (lane == 0) {
#pragma unroll
        for (int k = 0; k < K_TOP; ++k) {
            sel_idx[t * K_TOP + k] = selv[k];
            sel_w[t * K_TOP + k] = wvv[k] / wsum;
            atomicAdd(&counts[selv[k]], 1);
        }
    }
}

// ---------------- prefix scan + counts/entropy -----------------
__global__ void scan_stats_kernel(const int* __restrict__ counts,
                                  int* __restrict__ offsets, int* __restrict__ cursor,
                                  float* __restrict__ out_tail)
{
    if (threadIdx.x == 0 && blockIdx.x == 0) {
        int off = 0; float tot = 0.f;
        for (int e = 0; e < E_NUM; ++e) {
            offsets[e] = off; cursor[e] = off; off += counts[e];
            tot += (float)counts[e];
        }
        offsets[E_NUM] = off;
        const float total = fmaxf(tot, 1.f);
        float ent = 0.f;
        for (int e = 0; e < E_NUM; ++e) {
            const float c = (float)counts[e];
            const float frac = c / total;
            ent -= frac * logf(frac + 1e-6f);
            out_tail[e] = c;
        }
        out_tail[E_NUM] = ent;
    }
}

// ---------------- expert-grouped permutation (+ inverse) -----------------
__global__ void scatter_kernel(const int* __restrict__ sel_idx,
                               int* __restrict__ cursor, int* __restrict__ perm,
                               int* __restrict__ inv)
{
    const int i = blockIdx.x * 256 + threadIdx.x;
    if (i >= T_TOK * K_TOP) return;
    const int e = sel_idx[i];
    const int pos = atomicAdd(&cursor[e], 1);
    perm[pos] = i;
    inv[i] = pos;
}

// ---------------- x fp32 -> bf16 -----------------
__global__ __launch_bounds__(256) void convert_x_kernel(
    const float* __restrict__ x, __bf16* __restrict__ xb)
{
    const int i = blockIdx.x * 256 + threadIdx.x;
    const float4 a = reinterpret_cast<const float4*>(x)[i * 2];
    const float4 b = reinterpret_cast<const float4*>(x)[i * 2 + 1];
    bf16x8 o;
    o[0] = (__bf16)a.x; o[1] = (__bf16)a.y; o[2] = (__bf16)a.z; o[3] = (__bf16)a.w;
    o[4] = (__bf16)b.x; o[5] = (__bf16)b.y; o[6] = (__bf16)b.z; o[7] = (__bf16)b.w;
    reinterpret_cast<bf16x8*>(xb)[i] = o;
}

// ---------------- weight transpose fp32 [e][R][C] -> bf16 [e][C][R] ----------
__global__ __launch_bounds__(256) void transpose_w_kernel(
    const float* __restrict__ in, __bf16* __restrict__ out, int R, int C)
{
    const int e = blockIdx.z;
    const int r0 = blockIdx.y * 32, c0 = blockIdx.x * 32;
    const int tid = threadIdx.x;
    const int r = tid >> 3, c4 = (tid & 7) * 4;
    __shared__ float lds[32][33];
    const float4 v = *reinterpret_cast<const float4*>(
        in + (size_t)e * R * C + (size_t)(r0 + r) * C + c0 + c4);
    lds[c4 + 0][r] = v.x; lds[c4 + 1][r] = v.y;
    lds[c4 + 2][r] = v.z; lds[c4 + 3][r] = v.w;
    __syncthreads();
    bf16x4 o;
    o[0] = (__bf16)lds[r][c4 + 0]; o[1] = (__bf16)lds[r][c4 + 1];
    o[2] = (__bf16)lds[r][c4 + 2]; o[3] = (__bf16)lds[r][c4 + 3];
    *reinterpret_cast<bf16x4*>(out + (size_t)e * R * C + (size_t)(c0 + r) * R + r0 + c4) = o;
}

// ---------------- gate/up MFMA GEMM: 128 rows x (32 g + 32 u cols) -----------
__global__ __launch_bounds__(256) void gate_mfma_kernel(
    const __bf16* __restrict__ xb, const __bf16* __restrict__ wguT,
    const int* __restrict__ offsets, const int* __restrict__ perm,
    const float* __restrict__ sel_w, __bf16* __restrict__ h)
{
    const int e = blockIdx.z;
    const int base = offsets[e];
    const int nrows = offsets[e + 1] - base;
    const int m0 = blockIdx.y * 128;
    if (m0 >= nrows) return;
    const int c0 = blockIdx.x * 32;           // g-col tile (0..511, 16 tiles)

    __shared__ __align__(16) __bf16 As[128 * 32];
    __shared__ __align__(16) __bf16 Bg[32 * 32];
    __shared__ __align__(16) __bf16 Bu[32 * 32];
    __shared__ int   tokrow[128];
    __shared__ float wrow[128];

    const int tid = threadIdx.x;
    const int wv = tid >> 6, lane = tid & 63;

    if (tid < 128) {
        const int gr = m0 + tid;
        const int grc = min(gr, nrows - 1);
        const int pv = perm[base + grc];
        tokrow[tid] = pv >> 2;
        wrow[tid] = (gr < nrows) ? sel_w[pv] : 0.f;
    }
    __syncthreads();

    // A staging: 512 chunks of 8 bf16, 2 per thread
    const int ca0 = tid, ca1 = 256 + tid;
    const int ra0 = ca0 >> 2, ka0 = (ca0 & 3) ^ (ra0 & 3);
    const int ra1 = ca1 >> 2, ka1 = (ca1 & 3) ^ (ra1 & 3);
    const __bf16* a_src0 = xb + (size_t)tokrow[ra0] * D_DIM + ka0 * 8;
    const __bf16* a_src1 = xb + (size_t)tokrow[ra1] * D_DIM + ka1 * 8;
    // B staging: Bg 128 chunks (waves 0,1), Bu 128 chunks (waves 2,3)
    const int cbl = tid & 127;
    const int rb = cbl >> 2, kb = (cbl & 3) ^ (rb & 3);
    const size_t wbase = (size_t)e * D_DIM * TWOI;
    const __bf16* b_src = wguT + wbase +
        (size_t)(c0 + (tid < 128 ? 0 : 512) + rb) * D_DIM + kb * 8;
    __bf16* a_dst0 = As + wv * 512;
    __bf16* a_dst1 = As + 2048 + wv * 512;
    __bf16* b_dst = (wv < 2 ? Bg + wv * 512 : Bu + (wv - 2) * 512);

    const int wr = wv >> 1, wc = wv & 1;
    int a_off[4];
#pragma unroll
    for (int m = 0; m < 4; ++m) {
        const int row = wr * 64 + m * 16 + (lane & 15);
        a_off[m] = row * 32 + (((lane >> 4) ^ (row & 3)) << 3);
    }
    const int col = wc * 16 + (lane & 15);
    const int b_off = col * 32 + (((lane >> 4) ^ (col & 3)) << 3);

    f32x4 accg[4] = {}; f32x4 accu[4] = {};
    for (int d0 = 0; d0 < D_DIM; d0 += 32) {
        gload_lds16(a_src0 + d0, a_dst0);
        gload_lds16(a_src1 + d0, a_dst1);
        gload_lds16(b_src + d0, b_dst);
        __syncthreads();
        bf16x8 af[4];
#pragma unroll
        for (int m = 0; m < 4; ++m) af[m] = *reinterpret_cast<const bf16x8*>(&As[a_off[m]]);
        const bf16x8 bgf = *reinterpret_cast<const bf16x8*>(&Bg[b_off]);
        const bf16x8 buf = *reinterpret_cast<const bf16x8*>(&Bu[b_off]);
#pragma unroll
        for (int m = 0; m < 4; ++m) {
            accg[m] = __builtin_amdgcn_mfma_f32_16x16x32_bf16(af[m], bgf, accg[m], 0, 0, 0);
            accu[m] = __builtin_amdgcn_mfma_f32_16x16x32_bf16(af[m], buf, accu[m], 0, 0, 0);
        }
        __syncthreads();
    }

    const int ocol = c0 + wc * 16 + (lane & 15);
#pragma unroll
    for (int m = 0; m < 4; ++m)
#pragma unroll
        for (int j = 0; j < 4; ++j) {
            const int lr = wr * 64 + m * 16 + (lane >> 4) * 4 + j;
            const int gr = m0 + lr;
            if (gr < nrows) {
                const float g = accg[m][j];
                const float u = accu[m][j];
                const float s = g / (1.f + expf(-g));
                h[(size_t)(base + gr) * I_DIM + ocol] = (__bf16)(s * u * wrow[lr]);
            }
        }
}

// ---------------- down MFMA GEMM: 128 rows x 64 cols, partial rows out -------
__global__ __launch_bounds__(256) void down_mfma_p_kernel(
    const __bf16* __restrict__ h, const __bf16* __restrict__ wdnT,
    const int* __restrict__ offsets, float* __restrict__ yp)
{
    const int e = blockIdx.z;
    const int base = offsets[e];
    const int nrows = offsets[e + 1] - base;
    const int m0 = blockIdx.y * 128;
    if (m0 >= nrows) return;
    const int c0 = blockIdx.x * 64;          // 16 col tiles

    __shared__ __align__(16) __bf16 As[128 * 32];
    __shared__ __align__(16) __bf16 Bs[64 * 32];

    const int tid = threadIdx.x;
    const int wv = tid >> 6, lane = tid & 63;

    const int ca0 = tid, ca1 = 256 + tid;
    const int ra0 = ca0 >> 2, ka0 = (ca0 & 3) ^ (ra0 & 3);
    const int ra1 = ca1 >> 2, ka1 = (ca1 & 3) ^ (ra1 & 3);
    const __bf16* a_src0 = h + (size_t)(base + min(m0 + ra0, nrows - 1)) * I_DIM + ka0 * 8;
    const __bf16* a_src1 = h + (size_t)(base + min(m0 + ra1, nrows - 1)) * I_DIM + ka1 * 8;
    const int rb = tid >> 2, kb = (tid & 3) ^ (rb & 3);
    const size_t wbase = (size_t)e * I_DIM * D_DIM;
    const __bf16* b_src = wdnT + wbase + (size_t)(c0 + rb) * I_DIM + kb * 8;
    __bf16* a_dst0 = As + wv * 512;
    __bf16* a_dst1 = As + 2048 + wv * 512;
    __bf16* b_dst = Bs + wv * 512;

    const int wr = wv >> 1, wc = wv & 1;
    int a_off[4], b_off[2];
#pragma unroll
    for (int m = 0; m < 4; ++m) {
        const int row = wr * 64 + m * 16 + (lane & 15);
        a_off[m] = row * 32 + (((lane >> 4) ^ (row & 3)) << 3);
    }
#pragma unroll
    for (int n = 0; n < 2; ++n) {
        const int col = wc * 32 + n * 16 + (lane & 15);
        b_off[n] = col * 32 + (((lane >> 4) ^ (col & 3)) << 3);
    }

    f32x4 acc[4][2] = {};
    for (int d0 = 0; d0 < I_DIM; d0 += 32) {
        gload_lds16(a_src0 + d0, a_dst0);
        gload_lds16(a_src1 + d0, a_dst1);
        gload_lds16(b_src + d0, b_dst);
        __syncthreads();
        bf16x8 af[4], bf[2];
#pragma unroll
        for (int m = 0; m < 4; ++m) af[m] = *reinterpret_cast<const bf16x8*>(&As[a_off[m]]);
#pragma unroll
        for (int n = 0; n < 2; ++n) bf[n] = *reinterpret_cast<const bf16x8*>(&Bs[b_off[n]]);
#pragma unroll
        for (int m = 0; m < 4; ++m)
#pragma unroll
            for (int n = 0; n < 2; ++n)
                acc[m][n] = __builtin_amdgcn_mfma_f32_16x16x32_bf16(af[m], bf[n], acc[m][n], 0, 0, 0);
        __syncthreads();
    }

#pragma unroll
    for (int m = 0; m < 4; ++m)
#pragma unroll
        for (int j = 0; j < 4; ++j) {
            const int lr = wr * 64 + m * 16 + (lane >> 4) * 4 + j;
            const int gr = m0 + lr;
            if (gr < nrows) {
#pragma unroll
                for (int n = 0; n < 2; ++n) {
                    const int col = c0 + wc * 32 + n * 16 + (lane & 15);
                    yp[(size_t)(base + gr) * D_DIM + col] = acc[m][n][j];
                }
            }
        }
}

// ---------------- combine: y[t] = sum_k yp[inv[t*4+k]] -----------------------
__global__ __launch_bounds__(256) void combine_kernel(
    const float* __restrict__ yp, const int* __restrict__ inv, float* __restrict__ y)
{
    const int t = blockIdx.x, tid = threadIdx.x;
    const int r0 = inv[t * 4 + 0], r1 = inv[t * 4 + 1];
    const int r2 = inv[t * 4 + 2], r3 = inv[t * 4 + 3];
    const float4 a = reinterpret_cast<const float4*>(yp + (size_t)r0 * D_DIM)[tid];
    const float4 b = reinterpret_cast<const float4*>(yp + (size_t)r1 * D_DIM)[tid];
    const float4 c = reinterpret_cast<const float4*>(yp + (size_t)r2 * D_DIM)[tid];
    const float4 d = reinterpret_cast<const float4*>(yp + (size_t)r3 * D_DIM)[tid];
    float4 s;
    s.x = (a.x + b.x) + (c.x + d.x);
    s.y = (a.y + b.y) + (c.y + d.y);
    s.z = (a.z + b.z) + (c.z + d.z);
    s.w = (a.w + b.w) + (c.w + d.w);
    reinterpret_cast<float4*>(y + (size_t)t * D_DIM)[tid] = s;
}

// ---------------- down MFMA GEMM (mid tier): 128x128, atomic scatter ---------
__global__ __launch_bounds__(256) void down_mfma_kernel(
    const __bf16* __restrict__ h, const __bf16* __restrict__ wdnT,
    const int* __restrict__ offsets, const int* __restrict__ perm,
    float* __restrict__ y)
{
    const int e = blockIdx.z;
    const int base = offsets[e];
    const int nrows = offsets[e + 1] - base;
    const int m0 = blockIdx.y * 128;
    if (m0 >= nrows) return;
    const int c0 = blockIdx.x * 128;

    __shared__ __align__(16) __bf16 As[128 * 32];
    __shared__ __align__(16) __bf16 Bs[128 * 32];
    __shared__ int tokrow[128];

    const int tid = threadIdx.x;
    const int wv = tid >> 6, lane = tid & 63;

    if (tid < 128) {
        const int gr = m0 + tid;
        const int grc = min(gr, nrows - 1);
        tokrow[tid] = perm[base + grc] >> 2;
    }
    __syncthreads();

    const int ca0 = wv * 64 + lane, ca1 = 256 + wv * 64 + lane;
    const int ra0 = ca0 >> 2, ka0 = (ca0 & 3) ^ (ra0 & 3);
    const int ra1 = ca1 >> 2, ka1 = (ca1 & 3) ^ (ra1 & 3);
    const __bf16* a_src0 = h + (size_t)(base + min(m0 + ra0, nrows - 1)) * I_DIM + ka0 * 8;
    const __bf16* a_src1 = h + (size_t)(base + min(m0 + ra1, nrows - 1)) * I_DIM + ka1 * 8;
    const size_t wbase = (size_t)e * I_DIM * D_DIM;
    const __bf16* b_src0 = wdnT + wbase + (size_t)(c0 + ra0) * I_DIM + ka0 * 8;
    const __bf16* b_src1 = wdnT + wbase + (size_t)(c0 + ra1) * I_DIM + ka1 * 8;
    __bf16* a_dst0 = As + wv * 512;
    __bf16* a_dst1 = As + 2048 + wv * 512;
    __bf16* b_dst0 = Bs + wv * 512;
    __bf16* b_dst1 = Bs + 2048 + wv * 512;

    const int wr = wv >> 1, wc = wv & 1;
    int a_off[4], b_off[4];
#pragma unroll
    for (int m = 0; m < 4; ++m) {
        const int row = wr * 64 + m * 16 + (lane & 15);
        a_off[m] = row * 32 + (((lane >> 4) ^ (row & 3)) << 3);
        const int col = wc * 64 + m * 16 + (lane & 15);
        b_off[m] = col * 32 + (((lane >> 4) ^ (col & 3)) << 3);
    }

    f32x4 acc[4][4] = {};
    for (int d0 = 0; d0 < I_DIM; d0 += 32) {
        gload_lds16(a_src0 + d0, a_dst0);
        gload_lds16(a_src1 + d0, a_dst1);
        gload_lds16(b_src0 + d0, b_dst0);
        gload_lds16(b_src1 + d0, b_dst1);
        __syncthreads();
        bf16x8 af[4], bf[4];
#pragma unroll
        for (int m = 0; m < 4; ++m) {
            af[m] = *reinterpret_cast<const bf16x8*>(&As[a_off[m]]);
            bf[m] = *reinterpret_cast<const bf16x8*>(&Bs[b_off[m]]);
        }
#pragma unroll
        for (int m = 0; m < 4; ++m)
#pragma unroll
            for (int n = 0; n < 4; ++n)
                acc[m][n] = __builtin_amdgcn_mfma_f32_16x16x32_bf16(af[m], bf[n], acc[m][n], 0, 0, 0);
        __syncthreads();
    }

#pragma unroll
    for (int m = 0; m < 4; ++m)
#pragma unroll
        for (int j = 0; j < 4; ++j) {
            const int lr = wr * 64 + m * 16 + (lane >> 4) * 4 + j;
            const int gr = m0 + lr;
            if (gr < nrows) {
                const int tok = tokrow[lr];
#pragma unroll
                for (int n = 0; n < 4; ++n) {
                    const int col = c0 + wc * 64 + n * 16 + (lane & 15);
                    atomicAdd(&y[(size_t)tok * D_DIM + col], acc[m][n][j]);
                }
            }
        }
}

// ================= fallback fp32 path (round-0, proven) ======================
__global__ __launch_bounds__(256) void gate_gemm_kernel(
    const float* __restrict__ x, const float* __restrict__ wgu,
    const int* __restrict__ offsets, const int* __restrict__ perm,
    const float* __restrict__ sel_w, float* __restrict__ h)
{
    const int e = blockIdx.z;
    const int base = offsets[e];
    const int nrows = offsets[e + 1] - base;
    const int m0 = blockIdx.y * 64;
    if (m0 >= nrows) return;
    const int c0 = blockIdx.x * 64;
    const int tid = threadIdx.x;
    __shared__ float As[16][64];
    __shared__ float Bg[16][64];
    __shared__ float Bu[16][64];
    const int lrow = tid >> 2;
    const int c4 = (tid & 3) * 4;
    const int grow = m0 + lrow;
    const bool arow_ok = (grow < nrows);
    const float* xrow = nullptr;
    if (arow_ok) {
        const int pv = perm[base + grow];
        xrow = x + (size_t)(pv >> 2) * D_DIM;
    }
    const int bcol = tid & 63;
    const int brow0 = tid >> 6;
    const float* wbase = wgu + (size_t)e * D_DIM * TWOI;
    const int tx = tid & 15, ty = tid >> 4;
    float accg[4][4] = {}, accu[4][4] = {};
    for (int d0 = 0; d0 < D_DIM; d0 += 16) {
        float4 av = make_float4(0.f, 0.f, 0.f, 0.f);
        if (arow_ok) av = *reinterpret_cast<const float4*>(xrow + d0 + c4);
        As[c4 + 0][lrow] = av.x; As[c4 + 1][lrow] = av.y;
        As[c4 + 2][lrow] = av.z; As[c4 + 3][lrow] = av.w;
#pragma unroll
        for (int r = 0; r < 4; ++r) {
            const int dd = d0 + brow0 + r * 4;
            const float* wr = wbase + (size_t)dd * TWOI;
            Bg[brow0 + r * 4][bcol] = wr[c0 + bcol];
            Bu[brow0 + r * 4][bcol] = wr[c0 + 512 + bcol];
        }
        __syncthreads();
#pragma unroll
        for (int kk = 0; kk < 16; ++kk) {
            const float4 a  = *reinterpret_cast<const float4*>(&As[kk][ty * 4]);
            const float4 bg = *reinterpret_cast<const float4*>(&Bg[kk][tx * 4]);
            const float4 bu = *reinterpret_cast<const float4*>(&Bu[kk][tx * 4]);
            const float aa[4] = { a.x, a.y, a.z, a.w };
            const float gg[4] = { bg.x, bg.y, bg.z, bg.w };
            const float uu[4] = { bu.x, bu.y, bu.z, bu.w };
#pragma unroll
            for (int i2 = 0; i2 < 4; ++i2)
#pragma unroll
                for (int j = 0; j < 4; ++j) {
                    accg[i2][j] += aa[i2] * gg[j];
                    accu[i2][j] += aa[i2] * uu[j];
                }
        }
        __syncthreads();
    }
#pragma unroll
    for (int i2 = 0; i2 < 4; ++i2) {
        const int r = ty * 4 + i2;
        const int gr = m0 + r;
        if (gr < nrows) {
            const int pv = perm[base + gr];
            const float wgt = sel_w[pv];
            float* hrow = h + (size_t)(base + gr) * I_DIM + c0;
#pragma unroll
            for (int j = 0; j < 4; ++j) {
                const float g = accg[i2][j];
                const float u = accu[i2][j];
                const float s = g / (1.f + expf(-g));
                hrow[tx * 4 + j] = s * u * wgt;
            }
        }
    }
}

__global__ __launch_bounds__(256) void down_gemm_kernel(
    const float* __restrict__ h, const float* __restrict__ wdn,
    const int* __restrict__ offsets, const int* __restrict__ perm,
    float* __restrict__ y)
{
    const int e = blockIdx.z;
    const int base = offsets[e];
    const int nrows = offsets[e + 1] - base;
    const int m0 = blockIdx.y * 64;
    if (m0 >= nrows) return;
    const int c0 = blockIdx.x * 64;
    const int tid = threadIdx.x;
    __shared__ float As[16][64];
    __shared__ float Bs[16][64];
    const int lrow = tid >> 2;
    const int c4 = (tid & 3) * 4;
    const int grow = m0 + lrow;
    const bool arow_ok = (grow < nrows);
    const float* hrow = arow_ok ? (h + (size_t)(base + grow) * I_DIM) : nullptr;
    const int bcol = tid & 63;
    const int brow0 = tid >> 6;
    const float* wbase = wdn + (size_t)e * I_DIM * D_DIM;
    const int tx = tid & 15, ty = tid >> 4;
    float acc[4][4] = {};
    for (int d0 = 0; d0 < I_DIM; d0 += 16) {
        float4 av = make_float4(0.f, 0.f, 0.f, 0.f);
        if (arow_ok) av = *reinterpret_cast<const float4*>(hrow + d0 + c4);
        As[c4 + 0][lrow] = av.x; As[c4 + 1][lrow] = av.y;
        As[c4 + 2][lrow] = av.z; As[c4 + 3][lrow] = av.w;
#pragma unroll
        for (int r = 0; r < 4; ++r) {
            const int dd = d0 + brow0 + r * 4;
            Bs[brow0 + r * 4][bcol] = wbase[(size_t)dd * D_DIM + c0 + bcol];
        }
        __syncthreads();
#pragma unroll
        for (int kk = 0; kk < 16; ++kk) {
            const float4 a = *reinterpret_cast<const float4*>(&As[kk][ty * 4]);
            const float4 b = *reinterpret_cast<const float4*>(&Bs[kk][tx * 4]);
            const float aa[4] = { a.x, a.y, a.z, a.w };
            const float bb[4] = { b.x, b.y, b.z, b.w };
#pragma unroll
            for (int i2 = 0; i2 < 4; ++i2)
#pragma unroll
                for (int j = 0; j < 4; ++j)
                    acc[i2][j] += aa[i2] * bb[j];
        }
        __syncthreads();
    }
#pragma unroll
    for (int i2 = 0; i2 < 4; ++i2) {
        const int r = ty * 4 + i2;
        const int gr = m0 + r;
        if (gr < nrows) {
            const int pv = perm[base + gr];
            const int t = pv >> 2;
            float* yrow = y + (size_t)t * D_DIM + c0;
#pragma unroll
            for (int j = 0; j < 4; ++j)
                atomicAdd(&yrow[tx * 4 + j], acc[i2][j]);
        }
    }
}

// ---------------- launch -----------------------------------------------------
extern "C" void kernel_launch(void* const* d_in, const int* in_sizes, int n_in,
                              void* d_out, int out_size, void* d_ws, size_t ws_size,
                              hipStream_t stream)
{
    const float* x      = (const float*)d_in[0];
    const float* router = (const float*)d_in[1];
    const float* rbias  = (const float*)d_in[2];
    const float* wgu    = (const float*)d_in[3];
    const float* wdn    = (const float*)d_in[4];
    float* out = (float*)d_out;

    char* ws = (char*)d_ws;
    int*   sel_idx = (int*)(ws);                    // 32 KB
    float* sel_w   = (float*)(ws + 32768);          // 32 KB
    int*   perm    = (int*)(ws + 65536);            // 32 KB
    int*   inv     = (int*)(ws + 98304);            // 32 KB
    int*   counts  = (int*)(ws + 131072);
    int*   offsets = (int*)(ws + 131328);
    int*   cursor  = (int*)(ws + 131584);
    __bf16* xb     = (__bf16*)(ws + 262144);        // 4 MB
    __bf16* hb     = (__bf16*)(ws + 4456448);       // 8 MB
    __bf16* wguT   = (__bf16*)(ws + 12845056);      // 32 MB
    __bf16* wdnT   = (__bf16*)(ws + 46399488);      // 16 MB
    float* routerT = (float*)(ws + 63176704);       // 64 KB -> 63242240
    float* yp      = (float*)(ws + 63242240);       // 32 MB -> 96796672
    float* hf      = (float*)(ws + 262144);         // fallback fp32 h (16.8 MB)

    const bool fast = (ws_size >= 96796672ULL);
    const bool mid  = (ws_size >= 63242240ULL);

    hipMemsetAsync(counts, 0, 64, stream);
    if (!fast)
        hipMemsetAsync(out, 0, (size_t)T_TOK * D_DIM * sizeof(float), stream);

    if (mid) {
        transpose_router_kernel<<<64, 256, 0, stream>>>(router, routerT);
        router_fast_kernel<<<T_TOK / RTPB, 256, 0, stream>>>(x, routerT, rbias, sel_idx, sel_w, counts);
    } else {
        router_wave_kernel<<<T_TOK / 4, 256, 0, stream>>>(x, router, rbias, sel_idx, sel_w, counts);
    }
    scan_stats_kernel<<<1, 64, 0, stream>>>(counts, offsets, cursor,
                                            out + (size_t)T_TOK * D_DIM);
    scatter_kernel<<<(T_TOK * K_TOP + 255) / 256, 256, 0, stream>>>(sel_idx, cursor, perm, inv);

    if (mid) {
        convert_x_kernel<<<T_TOK * D_DIM / 8 / 256, 256, 0, stream>>>(x, xb);
        transpose_w_kernel<<<dim3(TWOI / 32, D_DIM / 32, E_NUM), 256, 0, stream>>>(wgu, wguT, D_DIM, TWOI);
        transpose_w_kernel<<<dim3(D_DIM / 32, I_DIM / 32, E_NUM), 256, 0, stream>>>(wdn, wdnT, I_DIM, D_DIM);
        gate_mfma_kernel<<<dim3(16, 16, E_NUM), 256, 0, stream>>>(xb, wguT, offsets, perm, sel_w, hb);
        if (fast) {
            down_mfma_p_kernel<<<dim3(16, 16, E_NUM), 256, 0, stream>>>(hb, wdnT, offsets, yp);
            combine_kernel<<<T_TOK, 256, 0, stream>>>(yp, inv, out);
        } else {
            down_mfma_kernel<<<dim3(8, 16, E_NUM), 256, 0, stream>>>(hb, wdnT, offsets, perm, out);
        }
    } else {
        gate_gemm_kernel<<<dim3(8, 32, E_NUM), 256, 0, stream>>>(x, wgu, offsets, perm, sel_w, hf);
        down_gemm_kernel<<<dim3(16, 32, E_NUM), 256, 0, stream>>>(hf, wdn, offsets, perm, out);
    }
}